// Round 2
// baseline (1957.688 us; speedup 1.0000x reference)
//
#include <hip/hip_runtime.h>
#include <cstddef>

// ---------------- problem constants ----------------
constexpr int Bb   = 4;
constexpr int Ll   = 13294;
constexpr int Cc   = 256;
constexpr int NHh  = 8;
constexpr int HDd  = 32;
constexpr int DFFd = 1024;
constexpr int NROW = Bb * Ll;   // 53176

constexpr int BM = 64, BN = 64, BK = 16;

// ---------------- tiled f32 GEMM: C = act(A @ B + bias) ----------------
// A: M x K row-major (optionally A+A2 elementwise), B: K x N row-major
template<bool ADD_A2, bool RELU>
__global__ __launch_bounds__(256)
void gemm_f32(const float* __restrict__ A, const float* __restrict__ A2,
              const float* __restrict__ Bm, const float* __restrict__ bias,
              float* __restrict__ Cm, int M, int N, int K)
{
    __shared__ float As[BK][BM];   // As[k][m]
    __shared__ float Bs[BK][BN];   // Bs[k][n]
    const int tid  = threadIdx.x;
    const int nb   = blockIdx.x, mb = blockIdx.y;
    const int row0 = mb * BM, col0 = nb * BN;
    const int tx = tid & 15, ty = tid >> 4;   // thread computes 4x4 at (ty*4, tx*4)
    float acc[4][4] = {};

    for (int k0 = 0; k0 < K; k0 += BK) {
        // ---- stage A tile (64x16): thread -> row tid>>2, 4 consecutive k
        {
            const int m  = tid >> 2;
            const int kk = (tid & 3) << 2;
            const int r  = row0 + m;
            float4 av = make_float4(0.f, 0.f, 0.f, 0.f);
            if (r < M) {
                av = *reinterpret_cast<const float4*>(&A[(size_t)r * K + k0 + kk]);
                if (ADD_A2) {
                    float4 a2 = *reinterpret_cast<const float4*>(&A2[(size_t)r * K + k0 + kk]);
                    av.x += a2.x; av.y += a2.y; av.z += a2.z; av.w += a2.w;
                }
            }
            As[kk + 0][m] = av.x; As[kk + 1][m] = av.y;
            As[kk + 2][m] = av.z; As[kk + 3][m] = av.w;
        }
        // ---- stage B tile (16x64): thread -> k = tid>>4, 4 consecutive n
        {
            const int k  = tid >> 4;
            const int nn = (tid & 15) << 2;
            float4 bv = *reinterpret_cast<const float4*>(&Bm[(size_t)(k0 + k) * N + col0 + nn]);
            *reinterpret_cast<float4*>(&Bs[k][nn]) = bv;
        }
        __syncthreads();
        #pragma unroll
        for (int k = 0; k < BK; ++k) {
            float a[4], b[4];
            *reinterpret_cast<float4*>(a) = *reinterpret_cast<const float4*>(&As[k][ty << 2]);
            *reinterpret_cast<float4*>(b) = *reinterpret_cast<const float4*>(&Bs[k][tx << 2]);
            #pragma unroll
            for (int i = 0; i < 4; ++i)
                #pragma unroll
                for (int j = 0; j < 4; ++j)
                    acc[i][j] = fmaf(a[i], b[j], acc[i][j]);
        }
        __syncthreads();
    }
    #pragma unroll
    for (int i = 0; i < 4; ++i) {
        const int r = row0 + (ty << 2) + i;
        if (r >= M) continue;
        #pragma unroll
        for (int j = 0; j < 4; ++j) {
            const int c = col0 + (tx << 2) + j;
            float vv = acc[i][j] + bias[c];
            if (RELU) vv = fmaxf(vv, 0.f);
            Cm[(size_t)r * N + c] = vv;
        }
    }
}

// ---------------- MSDA sampling ----------------
// one block per row (b,l); 8 groups of 32 lanes, group = head, lane = channel
__global__ __launch_bounds__(256)
void msda_sample(const float* __restrict__ v,     // [NROW, 256] head-major cols
                 const float* __restrict__ off,   // [NROW, 256]
                 const float* __restrict__ awl,   // [NROW, 128] logits
                 const float* __restrict__ refp,  // [NROW, 4, 2]
                 float* __restrict__ accO)        // [NROW, 256]
{
    const int row = blockIdx.x;
    const int d = threadIdx.x & 31;
    const int h = threadIdx.x >> 5;
    const int b = row / Ll;
    const int base_b = b * Ll;

    // softmax over 16 logits (redundant across lanes of the group; broadcast loads)
    float w[16];
    {
        const float* al = awl + (size_t)row * 128 + h * 16;
        float mx = -3.402823e38f;
        #pragma unroll
        for (int j = 0; j < 16; ++j) { w[j] = al[j]; mx = fmaxf(mx, w[j]); }
        float s = 0.f;
        #pragma unroll
        for (int j = 0; j < 16; ++j) { w[j] = __expf(w[j] - mx); s += w[j]; }
        const float inv = 1.f / s;
        #pragma unroll
        for (int j = 0; j < 16; ++j) w[j] *= inv;
    }

    const float* offr = off + (size_t)row * 256 + h * 32;
    const float* rp   = refp + (size_t)row * 8;
    const int Hs[4] = {100, 50, 25, 13};
    const int Ws[4] = {100, 50, 25, 13};
    const int Ss[4] = {0, 10000, 12500, 13125};

    float accv = 0.f;
    #pragma unroll
    for (int lvl = 0; lvl < 4; ++lvl) {
        const float W_ = (float)Ws[lvl], H_ = (float)Hs[lvl];
        const float rx = rp[lvl * 2 + 0], ry = rp[lvl * 2 + 1];
        const float* vb = v + (size_t)(base_b + Ss[lvl]) * 256 + h * 32 + d;
        #pragma unroll
        for (int p = 0; p < 4; ++p) {
            const float ox = offr[(lvl * 4 + p) * 2 + 0];
            const float oy = offr[(lvl * 4 + p) * 2 + 1];
            // match reference arithmetic: loc = ref + off/norm; pix = loc*size - 0.5
            const float locx = rx + ox / W_;
            const float locy = ry + oy / H_;
            const float x = locx * W_ - 0.5f;
            const float y = locy * H_ - 0.5f;
            const float x0f = floorf(x), y0f = floorf(y);
            const float lx = x - x0f, ly = y - y0f;
            const int x0 = (int)x0f, y0 = (int)y0f;
            float sv = 0.f;
            #pragma unroll
            for (int cy = 0; cy < 2; ++cy) {
                #pragma unroll
                for (int cx = 0; cx < 2; ++cx) {
                    const int yi = y0 + cy, xi = x0 + cx;
                    const bool ok = (yi >= 0) && (yi < Hs[lvl]) && (xi >= 0) && (xi < Ws[lvl]);
                    const int yc = min(max(yi, 0), Hs[lvl] - 1);
                    const int xc = min(max(xi, 0), Ws[lvl] - 1);
                    const float wt = (cy ? ly : 1.f - ly) * (cx ? lx : 1.f - lx);
                    const float val = vb[(size_t)(yc * Ws[lvl] + xc) * 256];
                    sv = fmaf(ok ? wt : 0.f, val, sv);
                }
            }
            accv = fmaf(w[lvl * 4 + p], sv, accv);
        }
    }
    accO[(size_t)row * 256 + h * 32 + d] = accv;
}

// ---------------- fused residual + LayerNorm (one wave per 256-col row) ----
__global__ __launch_bounds__(256)
void ln_fused(const float* __restrict__ a, const float* __restrict__ bres,
              const float* __restrict__ g, const float* __restrict__ be,
              float* __restrict__ out, int M)
{
    const int lane = threadIdx.x & 63;
    const int wv = threadIdx.x >> 6;
    const int row = blockIdx.x * 4 + wv;
    if (row >= M) return;
    const size_t base = (size_t)row * 256 + lane * 4;
    float4 x1 = *reinterpret_cast<const float4*>(&a[base]);
    float4 x2 = *reinterpret_cast<const float4*>(&bres[base]);
    float xs[4] = {x1.x + x2.x, x1.y + x2.y, x1.z + x2.z, x1.w + x2.w};
    float s = xs[0] + xs[1] + xs[2] + xs[3];
    float q = xs[0] * xs[0] + xs[1] * xs[1] + xs[2] * xs[2] + xs[3] * xs[3];
    #pragma unroll
    for (int o = 32; o >= 1; o >>= 1) {
        s += __shfl_xor(s, o, 64);
        q += __shfl_xor(q, o, 64);
    }
    const float mean = s * (1.f / 256.f);
    const float var = q * (1.f / 256.f) - mean * mean;
    const float r = rsqrtf(var + 1e-5f);
    float4 gv = *reinterpret_cast<const float4*>(&g[lane * 4]);
    float4 bv = *reinterpret_cast<const float4*>(&be[lane * 4]);
    float4 o4;
    o4.x = (xs[0] - mean) * r * gv.x + bv.x;
    o4.y = (xs[1] - mean) * r * gv.y + bv.y;
    o4.z = (xs[2] - mean) * r * gv.z + bv.z;
    o4.w = (xs[3] - mean) * r * gv.w + bv.w;
    *reinterpret_cast<float4*>(&out[base]) = o4;
}

// ---------------- launcher ----------------
extern "C" void kernel_launch(void* const* d_in, const int* in_sizes, int n_in,
                              void* d_out, int out_size, void* d_ws, size_t ws_size,
                              hipStream_t stream)
{
    (void)in_sizes; (void)n_in; (void)out_size; (void)ws_size;
    const float* query = (const float*)d_in[0];
    const float* qpos  = (const float*)d_in[1];
    const float* refp  = (const float*)d_in[2];
    const float* v_W   = (const float*)d_in[5];
    const float* v_b   = (const float*)d_in[6];
    const float* off_W = (const float*)d_in[7];
    const float* off_b = (const float*)d_in[8];
    const float* aw_W  = (const float*)d_in[9];
    const float* aw_b  = (const float*)d_in[10];
    const float* out_W = (const float*)d_in[11];
    const float* out_b = (const float*)d_in[12];
    const float* ln1g  = (const float*)d_in[13];
    const float* ln1b  = (const float*)d_in[14];
    const float* w1    = (const float*)d_in[15];
    const float* b1    = (const float*)d_in[16];
    const float* w2    = (const float*)d_in[17];
    const float* b2    = (const float*)d_in[18];
    const float* ln2g  = (const float*)d_in[19];
    const float* ln2b  = (const float*)d_in[20];
    float* out = (float*)d_out;

    char* ws = (char*)d_ws;
    const size_t SZ = (size_t)NROW * 256 * 4;  // 54,452,224 B
    // slot plan (peak 3.25*SZ ~= 177 MB):
    //   [0,SZ)        : v      -> later src2
    //   [SZ,2SZ)      : off    -> later x
    //   [2SZ,2.5SZ)   : awl    -> later (ffn1 overlays [2SZ,3SZ))
    //   [2.5SZ,3.5SZ) : acc    -> later ffn2 at [3SZ,3.25SZ)
    float* vbuf = (float*)(ws);
    float* offb = (float*)(ws + SZ);
    float* awlb = (float*)(ws + 2 * SZ);
    float* accb = (float*)(ws + 2 * SZ + SZ / 2);
    float* src2 = (float*)(ws);
    float* xbuf = (float*)(ws + SZ);
    float* ffn1 = (float*)(ws + 2 * SZ);
    float* ffn2 = (float*)(ws + 3 * SZ);

    dim3 blk(256);
    const int MB_ = (NROW + BM - 1) / BM;  // 831

    // 1. v = query @ v_W + v_b
    gemm_f32<false, false><<<dim3(256 / BN, MB_), blk, 0, stream>>>(
        query, nullptr, v_W, v_b, vbuf, NROW, 256, 256);
    // 2. off = (query+qpos) @ off_W + off_b
    gemm_f32<true, false><<<dim3(256 / BN, MB_), blk, 0, stream>>>(
        query, qpos, off_W, off_b, offb, NROW, 256, 256);
    // 3. aw logits
    gemm_f32<true, false><<<dim3(128 / BN, MB_), blk, 0, stream>>>(
        query, qpos, aw_W, aw_b, awlb, NROW, 128, 256);
    // 4. deformable sampling
    msda_sample<<<NROW, 256, 0, stream>>>(vbuf, offb, awlb, refp, accb);
    // 5. src2 = acc @ out_W + out_b
    gemm_f32<false, false><<<dim3(256 / BN, MB_), blk, 0, stream>>>(
        accb, nullptr, out_W, out_b, src2, NROW, 256, 256);
    // 6. x = LN(query + src2)
    ln_fused<<<(NROW + 3) / 4, blk, 0, stream>>>(query, src2, ln1g, ln1b, xbuf, NROW);
    // 7. FFN in 4 row-chunks (ffn1 chunk = 13294*1024*4 B = SZ)
    const int CH = 4, CR = NROW / CH;  // 13294
    const int MBc = (CR + BM - 1) / BM;
    for (int c = 0; c < CH; ++c) {
        const float* xrow = xbuf + (size_t)c * CR * 256;
        gemm_f32<false, true><<<dim3(1024 / BN, MBc), blk, 0, stream>>>(
            xrow, nullptr, w1, b1, ffn1, CR, 1024, 256);
        gemm_f32<false, false><<<dim3(256 / BN, MBc), blk, 0, stream>>>(
            ffn1, nullptr, w2, b2, ffn2, CR, 256, 1024);
        ln_fused<<<(CR + 3) / 4, blk, 0, stream>>>(
            xrow, ffn2, ln2g, ln2b, out + (size_t)c * CR * 256, CR);
    }
}

// Round 3
// 710.328 us; speedup vs baseline: 2.7560x; 2.7560x over previous
//
#include <hip/hip_runtime.h>
#include <hip/hip_bf16.h>
#include <cstddef>

// ---------------- problem constants ----------------
constexpr int Ll   = 13294;
constexpr int NROW = 4 * Ll;     // 53176
constexpr int MP   = 53248;      // rows padded to multiple of 128
constexpr int CRp  = MP / 2;     // 26624 (FFN chunk rows)

typedef __bf16       bf8v __attribute__((ext_vector_type(8)));
typedef float        f4v  __attribute__((ext_vector_type(4)));
typedef unsigned int u4v  __attribute__((ext_vector_type(4)));

// =====================================================================
// bf16 MFMA GEMM, m97 structure: 128x128 tile, BK=32, 4 waves (2x2),
// global_load_lds(16B) staging, 16x16x32 bf16 MFMA, f32 accum.
// A: [M][K] bf16 row-major (M padded to 128). Bt: [N][K] bf16 (W^T).
// =====================================================================
template<bool RELU, bool OUTF, bool OUTB>
__global__ __launch_bounds__(256)
void gemm_mfma(const __hip_bfloat16* __restrict__ A, const __hip_bfloat16* __restrict__ Bt,
               const float* __restrict__ bias, float* __restrict__ Cf,
               __hip_bfloat16* __restrict__ Cb, int M, int N, int K)
{
    __shared__ __hip_bfloat16 As[128 * 32];
    __shared__ __hip_bfloat16 Bs[128 * 32];
    const int tid  = threadIdx.x;
    const int wid  = tid >> 6;
    const int lane = tid & 63;
    const int m0 = blockIdx.y * 128;
    const int n0 = blockIdx.x * 128;
    const int wm = wid >> 1, wn = wid & 1;     // wave tile 64x64
    const int fr = lane & 15, fq = lane >> 4;  // fragment row/col + k-group

    const int sr = lane >> 2;        // staging: row within 16-row segment
    const int sc = (lane & 3) * 8;   // staging: elem col within BK=32

    f4v acc[4][4] = {};

    for (int k0 = 0; k0 < K; k0 += 32) {
        #pragma unroll
        for (int i = 0; i < 2; ++i) {
            const int s = wid * 2 + i;   // 16-row segment id, 0..7
            const __hip_bfloat16* sa = A  + (size_t)(m0 + s * 16 + sr) * K + k0 + sc;
            const __hip_bfloat16* sb = Bt + (size_t)(n0 + s * 16 + sr) * K + k0 + sc;
            __builtin_amdgcn_global_load_lds(
                (const __attribute__((address_space(1))) void*)sa,
                (__attribute__((address_space(3))) void*)&As[s * 512], 16, 0, 0);
            __builtin_amdgcn_global_load_lds(
                (const __attribute__((address_space(1))) void*)sb,
                (__attribute__((address_space(3))) void*)&Bs[s * 512], 16, 0, 0);
        }
        __syncthreads();

        bf8v a[4], b[4];
        #pragma unroll
        for (int r = 0; r < 4; ++r) {
            a[r] = __builtin_bit_cast(bf8v, *(const u4v*)&As[(wm * 64 + r * 16 + fr) * 32 + fq * 8]);
            b[r] = __builtin_bit_cast(bf8v, *(const u4v*)&Bs[(wn * 64 + r * 16 + fr) * 32 + fq * 8]);
        }
        #pragma unroll
        for (int mr = 0; mr < 4; ++mr)
            #pragma unroll
            for (int nr = 0; nr < 4; ++nr)
                acc[mr][nr] = __builtin_amdgcn_mfma_f32_16x16x32_bf16(a[mr], b[nr], acc[mr][nr], 0, 0, 0);
        __syncthreads();
    }

    // epilogue: C/D layout col = lane&15, row = (lane>>4)*4 + j  [m89/m91]
    #pragma unroll
    for (int nr = 0; nr < 4; ++nr) {
        const int col = n0 + wn * 64 + nr * 16 + fr;
        const float bb = bias[col];
        #pragma unroll
        for (int mr = 0; mr < 4; ++mr) {
            const int rowb = m0 + wm * 64 + mr * 16 + fq * 4;
            #pragma unroll
            for (int j = 0; j < 4; ++j) {
                float v = acc[mr][nr][j] + bb;
                if (RELU) v = fmaxf(v, 0.f);
                if (OUTF) Cf[(size_t)(rowb + j) * N + col] = v;
                if (OUTB) Cb[(size_t)(rowb + j) * N + col] = __float2bfloat16(v);
            }
        }
    }
}

// =====================================================================
// f32 -> bf16 row conversion (optionally fused add), pad rows -> 0
// =====================================================================
template<bool ADD>
__global__ __launch_bounds__(256)
void cvt_bf16_rows(const float* __restrict__ a, const float* __restrict__ a2,
                   __hip_bfloat16* __restrict__ o)
{
    const int i   = blockIdx.x * 256 + threadIdx.x;  // 8-elem chunk id
    const int row = i >> 5;                           // 32 chunks per 256-col row
    union { u4v u; __hip_bfloat16 h[8]; } pk;
    if (row >= NROW) {
        u4v z = {0u, 0u, 0u, 0u};
        pk.u = z;
    } else {
        const size_t e = (size_t)i * 8;
        float4 x0 = *(const float4*)&a[e];
        float4 x1 = *(const float4*)&a[e + 4];
        if (ADD) {
            float4 y0 = *(const float4*)&a2[e];
            float4 y1 = *(const float4*)&a2[e + 4];
            x0.x += y0.x; x0.y += y0.y; x0.z += y0.z; x0.w += y0.w;
            x1.x += y1.x; x1.y += y1.y; x1.z += y1.z; x1.w += y1.w;
        }
        pk.h[0] = __float2bfloat16(x0.x); pk.h[1] = __float2bfloat16(x0.y);
        pk.h[2] = __float2bfloat16(x0.z); pk.h[3] = __float2bfloat16(x0.w);
        pk.h[4] = __float2bfloat16(x1.x); pk.h[5] = __float2bfloat16(x1.y);
        pk.h[6] = __float2bfloat16(x1.z); pk.h[7] = __float2bfloat16(x1.w);
    }
    *(u4v*)&o[(size_t)i * 8] = pk.u;
}

// ---------------- weight transpose + bf16 convert: Wt[n][k] = W[k][n] ----
__global__ __launch_bounds__(256)
void transpose_w(const float* __restrict__ W, __hip_bfloat16* __restrict__ Wt, int K, int N)
{
    const int i = blockIdx.x * 256 + threadIdx.x;
    if (i >= N * K) return;
    const int n = i / K, k = i - n * K;
    Wt[i] = __float2bfloat16(W[(size_t)k * N + n]);
}

// =====================================================================
// MSDA sampling, two-phase:
//  phase 1 (128 thr): per (head,point) softmax weight + 4 corner byte
//                     offsets & combined weights -> LDS
//  phase 2 (256 thr): (head, channel) gathers: 64 bf16 loads + fma
// =====================================================================
__global__ __launch_bounds__(256)
void msda_sample2(const __hip_bfloat16* __restrict__ v, const float* __restrict__ off,
                  const float* __restrict__ awl, const float* __restrict__ refp,
                  __hip_bfloat16* __restrict__ accO)
{
    __shared__ int   sIdx[128][4];
    __shared__ float sW[128][4];
    const int row = blockIdx.x;
    const int tid = threadIdx.x;

    if (tid < 128) {
        const int h = tid >> 4, p = tid & 15;
        const int lvl = p >> 2;
        const float logit = awl[(size_t)row * 128 + h * 16 + p];
        float mx = logit;
        #pragma unroll
        for (int o = 1; o < 16; o <<= 1) mx = fmaxf(mx, __shfl_xor(mx, o, 64));
        const float e = __expf(logit - mx);
        float s = e;
        #pragma unroll
        for (int o = 1; o < 16; o <<= 1) s += __shfl_xor(s, o, 64);
        const float aw = e / s;

        const int   Hs[4]  = {100, 50, 25, 13};
        const int   Wsz[4] = {100, 50, 25, 13};
        const int   Ss[4]  = {0, 10000, 12500, 13125};
        const float W_ = (float)Wsz[lvl], H_ = (float)Hs[lvl];
        const float ox = off[(size_t)row * 256 + h * 32 + p * 2 + 0];
        const float oy = off[(size_t)row * 256 + h * 32 + p * 2 + 1];
        const float rx = refp[(size_t)row * 8 + lvl * 2 + 0];
        const float ry = refp[(size_t)row * 8 + lvl * 2 + 1];
        const float x = (rx + ox / W_) * W_ - 0.5f;   // keep reference op order
        const float y = (ry + oy / H_) * H_ - 0.5f;
        const float x0f = floorf(x), y0f = floorf(y);
        const float lx = x - x0f, ly = y - y0f;
        const int x0 = (int)x0f, y0 = (int)y0f;
        const int b = row / Ll;
        const int vbase = b * Ll + Ss[lvl];
        #pragma unroll
        for (int c = 0; c < 4; ++c) {
            const int cy = c >> 1, cx = c & 1;
            const int yi = y0 + cy, xi = x0 + cx;
            const bool ok = (yi >= 0) & (yi < Hs[lvl]) & (xi >= 0) & (xi < Wsz[lvl]);
            const int yc = min(max(yi, 0), Hs[lvl] - 1);
            const int xc = min(max(xi, 0), Wsz[lvl] - 1);
            const float wt = (cy ? ly : 1.f - ly) * (cx ? lx : 1.f - lx);
            sIdx[tid][c] = (vbase + yc * Wsz[lvl] + xc) * 512;   // byte offset of v-row
            sW[tid][c]   = ok ? aw * wt : 0.f;
        }
    }
    __syncthreads();

    const int d = tid & 31, h = tid >> 5;
    const char* vB = (const char*)v + (h * 32 + d) * 2;
    float acc = 0.f;
    #pragma unroll
    for (int i = 0; i < 16; ++i) {
        const int4   ix = *reinterpret_cast<const int4*>(&sIdx[h * 16 + i][0]);
        const float4 wv = *reinterpret_cast<const float4*>(&sW[h * 16 + i][0]);
        const float v0 = __bfloat162float(*(const __hip_bfloat16*)(vB + (unsigned)ix.x));
        const float v1 = __bfloat162float(*(const __hip_bfloat16*)(vB + (unsigned)ix.y));
        const float v2 = __bfloat162float(*(const __hip_bfloat16*)(vB + (unsigned)ix.z));
        const float v3 = __bfloat162float(*(const __hip_bfloat16*)(vB + (unsigned)ix.w));
        acc = fmaf(wv.x, v0, acc);
        acc = fmaf(wv.y, v1, acc);
        acc = fmaf(wv.z, v2, acc);
        acc = fmaf(wv.w, v3, acc);
    }
    accO[(size_t)row * 256 + h * 32 + d] = __float2bfloat16(acc);
}

// =====================================================================
// residual + LayerNorm; optional bf16 copy of output; pad rows -> 0
// =====================================================================
template<bool WB>
__global__ __launch_bounds__(256)
void ln_fused2(const float* __restrict__ a, const float* __restrict__ res,
               const float* __restrict__ g, const float* __restrict__ be,
               float* __restrict__ outF, __hip_bfloat16* __restrict__ outB,
               int Mreal, int Mtot)
{
    const int lane = threadIdx.x & 63;
    const int wv   = threadIdx.x >> 6;
    const int row  = blockIdx.x * 4 + wv;
    if (row >= Mtot) return;
    const size_t base = (size_t)row * 256 + lane * 4;
    if (row >= Mreal) {
        float4 z = make_float4(0.f, 0.f, 0.f, 0.f);
        *(float4*)&outF[base] = z;
        if (WB) { union { ushort4 u; __hip_bfloat16 h[4]; } pk;
                  pk.h[0] = pk.h[1] = pk.h[2] = pk.h[3] = __float2bfloat16(0.f);
                  *(ushort4*)&outB[base] = pk.u; }
        return;
    }
    float4 x1 = *(const float4*)&a[base];
    float4 x2 = *(const float4*)&res[base];
    float xs[4] = {x1.x + x2.x, x1.y + x2.y, x1.z + x2.z, x1.w + x2.w};
    float s = xs[0] + xs[1] + xs[2] + xs[3];
    float q = xs[0]*xs[0] + xs[1]*xs[1] + xs[2]*xs[2] + xs[3]*xs[3];
    #pragma unroll
    for (int o = 32; o >= 1; o >>= 1) {
        s += __shfl_xor(s, o, 64);
        q += __shfl_xor(q, o, 64);
    }
    const float mean = s * (1.f / 256.f);
    const float var  = q * (1.f / 256.f) - mean * mean;
    const float r    = rsqrtf(var + 1e-5f);
    float4 gv = *(const float4*)&g[lane * 4];
    float4 bv = *(const float4*)&be[lane * 4];
    float o0 = (xs[0] - mean) * r * gv.x + bv.x;
    float o1 = (xs[1] - mean) * r * gv.y + bv.y;
    float o2 = (xs[2] - mean) * r * gv.z + bv.z;
    float o3 = (xs[3] - mean) * r * gv.w + bv.w;
    float4 o4 = make_float4(o0, o1, o2, o3);
    *(float4*)&outF[base] = o4;
    if (WB) {
        union { ushort4 u; __hip_bfloat16 h[4]; } pk;
        pk.h[0] = __float2bfloat16(o0); pk.h[1] = __float2bfloat16(o1);
        pk.h[2] = __float2bfloat16(o2); pk.h[3] = __float2bfloat16(o3);
        *(ushort4*)&outB[base] = pk.u;
    }
}

// =====================================================================
// launcher
// =====================================================================
extern "C" void kernel_launch(void* const* d_in, const int* in_sizes, int n_in,
                              void* d_out, int out_size, void* d_ws, size_t ws_size,
                              hipStream_t stream)
{
    (void)in_sizes; (void)n_in; (void)out_size; (void)ws_size;
    const float* query = (const float*)d_in[0];
    const float* qpos  = (const float*)d_in[1];
    const float* refp  = (const float*)d_in[2];
    const float* v_W   = (const float*)d_in[5];
    const float* v_b   = (const float*)d_in[6];
    const float* off_W = (const float*)d_in[7];
    const float* off_b = (const float*)d_in[8];
    const float* aw_W  = (const float*)d_in[9];
    const float* aw_b  = (const float*)d_in[10];
    const float* out_W = (const float*)d_in[11];
    const float* out_b = (const float*)d_in[12];
    const float* ln1g  = (const float*)d_in[13];
    const float* ln1b  = (const float*)d_in[14];
    const float* w1    = (const float*)d_in[15];
    const float* b1    = (const float*)d_in[16];
    const float* w2    = (const float*)d_in[17];
    const float* b2    = (const float*)d_in[18];
    const float* ln2g  = (const float*)d_in[19];
    const float* ln2b  = (const float*)d_in[20];
    float* out = (float*)d_out;

    char* ws = (char*)d_ws;
    const size_t SZp = (size_t)MP * 256 * 4;   // 54,525,952 B
    // live-range slot plan (peak 3*SZp + 1.5 MB ~= 165 MB):
    float*          offb = (float*)(ws);                                // [0, 1.0)
    float*          awlb = (float*)(ws + SZp);                          // [1.0, 1.5)
    __hip_bfloat16* qb   = (__hip_bfloat16*)(ws + SZp + SZp / 2);       // [1.5, 2.0)
    __hip_bfloat16* qpb  = (__hip_bfloat16*)(ws + 2 * SZp);             // [2.0, 2.5)
    __hip_bfloat16* vbuf = (__hip_bfloat16*)(ws + 2 * SZp + SZp / 2);   // [2.5, 3.0)
    __hip_bfloat16* accb = qb;                                          // qb dead
    float*          src2 = (float*)(ws);                                // offb dead
    float*          xf   = (float*)(ws + SZp);                          // awlb/accb dead
    __hip_bfloat16* xb   = (__hip_bfloat16*)(ws + 2 * SZp);             // qpb dead
    __hip_bfloat16* hbuf = (__hip_bfloat16*)(ws);                       // src2 dead
    float*          f2f  = (float*)(ws + 2 * SZp + SZp / 2);            // vbuf dead
    char* wsw = ws + 3 * SZp;
    __hip_bfloat16* vWt   = (__hip_bfloat16*)(wsw);
    __hip_bfloat16* offWt = (__hip_bfloat16*)(wsw + 131072);
    __hip_bfloat16* awWt  = (__hip_bfloat16*)(wsw + 262144);
    __hip_bfloat16* outWt = (__hip_bfloat16*)(wsw + 327680);
    __hip_bfloat16* w1t   = (__hip_bfloat16*)(wsw + 458752);
    __hip_bfloat16* w2t   = (__hip_bfloat16*)(wsw + 983040);

    dim3 blk(256);

    // weights -> bf16 transposed
    transpose_w<<<256,  blk, 0, stream>>>(v_W,   vWt,   256, 256);
    transpose_w<<<256,  blk, 0, stream>>>(off_W, offWt, 256, 256);
    transpose_w<<<128,  blk, 0, stream>>>(aw_W,  awWt,  256, 128);
    transpose_w<<<256,  blk, 0, stream>>>(out_W, outWt, 256, 256);
    transpose_w<<<1024, blk, 0, stream>>>(w1,    w1t,   256, 1024);
    transpose_w<<<1024, blk, 0, stream>>>(w2,    w2t,   1024, 256);
    // activations -> bf16 (padded)
    cvt_bf16_rows<false><<<MP / 8, blk, 0, stream>>>(query, nullptr, qb);
    cvt_bf16_rows<true ><<<MP / 8, blk, 0, stream>>>(query, qpos, qpb);

    // projections
    gemm_mfma<false, false, true><<<dim3(2, MP / 128), blk, 0, stream>>>(
        qb, vWt, v_b, nullptr, vbuf, MP, 256, 256);
    gemm_mfma<false, true, false><<<dim3(2, MP / 128), blk, 0, stream>>>(
        qpb, offWt, off_b, offb, nullptr, MP, 256, 256);
    gemm_mfma<false, true, false><<<dim3(1, MP / 128), blk, 0, stream>>>(
        qpb, awWt, aw_b, awlb, nullptr, MP, 128, 256);

    // deformable sampling
    msda_sample2<<<NROW, blk, 0, stream>>>(vbuf, offb, awlb, refp, accb);

    // output projection + LN1
    gemm_mfma<false, true, false><<<dim3(2, MP / 128), blk, 0, stream>>>(
        accb, outWt, out_b, src2, nullptr, MP, 256, 256);
    ln_fused2<true><<<MP / 4, blk, 0, stream>>>(query, src2, ln1g, ln1b, xf, xb, NROW, MP);

    // FFN in 2 row-chunks + LN2
    for (int c = 0; c < 2; ++c) {
        gemm_mfma<true, false, true><<<dim3(8, CRp / 128), blk, 0, stream>>>(
            xb + (size_t)c * CRp * 256, w1t, b1, nullptr, hbuf, CRp, 1024, 256);
        gemm_mfma<false, true, false><<<dim3(2, CRp / 128), blk, 0, stream>>>(
            hbuf, w2t, b2, f2f, nullptr, CRp, 256, 1024);
        const int rr = (c == 0) ? CRp : (NROW - CRp);
        ln_fused2<false><<<(rr + 3) / 4, blk, 0, stream>>>(
            xf + (size_t)c * CRp * 256, f2f, ln2g, ln2b,
            out + (size_t)c * CRp * 256, nullptr, rr, rr);
    }
}

// Round 4
// 417.332 us; speedup vs baseline: 4.6910x; 1.7021x over previous
//
#include <hip/hip_runtime.h>
#include <hip/hip_bf16.h>
#include <cstddef>

// ---------------- problem constants ----------------
constexpr int Ll   = 13294;
constexpr int NROW = 4 * Ll;     // 53176
constexpr int MP   = 53248;      // rows padded to multiple of 128
constexpr int CRp  = MP / 2;     // 26624 (FFN chunk rows)

typedef __bf16       bf8v __attribute__((ext_vector_type(8)));
typedef float        f4v  __attribute__((ext_vector_type(4)));
typedef unsigned int u4v  __attribute__((ext_vector_type(4)));

// =====================================================================
// bf16 MFMA GEMM, m97 structure: 128x128 tile, BK=32, 4 waves (2x2),
// global_load_lds(16B) staging, 16x16x32 bf16 MFMA, f32 accum.
// A: [M][K] bf16 row-major (M padded to 128). Bt: [N][K] bf16 (W^T).
// =====================================================================
template<bool RELU, bool OUTF, bool OUTB>
__global__ __launch_bounds__(256)
void gemm_mfma(const __hip_bfloat16* __restrict__ A, const __hip_bfloat16* __restrict__ Bt,
               const float* __restrict__ bias, float* __restrict__ Cf,
               __hip_bfloat16* __restrict__ Cb, int M, int N, int K)
{
    __shared__ __hip_bfloat16 As[128 * 32];
    __shared__ __hip_bfloat16 Bs[128 * 32];
    const int tid  = threadIdx.x;
    const int wid  = tid >> 6;
    const int lane = tid & 63;
    const int m0 = blockIdx.y * 128;
    const int n0 = blockIdx.x * 128;
    const int wm = wid >> 1, wn = wid & 1;     // wave tile 64x64
    const int fr = lane & 15, fq = lane >> 4;  // fragment row/col + k-group

    const int sr = lane >> 2;        // staging: row within 16-row segment
    const int sc = (lane & 3) * 8;   // staging: elem col within BK=32

    f4v acc[4][4] = {};

    for (int k0 = 0; k0 < K; k0 += 32) {
        #pragma unroll
        for (int i = 0; i < 2; ++i) {
            const int s = wid * 2 + i;   // 16-row segment id, 0..7
            const __hip_bfloat16* sa = A  + (size_t)(m0 + s * 16 + sr) * K + k0 + sc;
            const __hip_bfloat16* sb = Bt + (size_t)(n0 + s * 16 + sr) * K + k0 + sc;
            __builtin_amdgcn_global_load_lds(
                (const __attribute__((address_space(1))) void*)sa,
                (__attribute__((address_space(3))) void*)&As[s * 512], 16, 0, 0);
            __builtin_amdgcn_global_load_lds(
                (const __attribute__((address_space(1))) void*)sb,
                (__attribute__((address_space(3))) void*)&Bs[s * 512], 16, 0, 0);
        }
        __syncthreads();

        bf8v a[4], b[4];
        #pragma unroll
        for (int r = 0; r < 4; ++r) {
            a[r] = __builtin_bit_cast(bf8v, *(const u4v*)&As[(wm * 64 + r * 16 + fr) * 32 + fq * 8]);
            b[r] = __builtin_bit_cast(bf8v, *(const u4v*)&Bs[(wn * 64 + r * 16 + fr) * 32 + fq * 8]);
        }
        #pragma unroll
        for (int mr = 0; mr < 4; ++mr)
            #pragma unroll
            for (int nr = 0; nr < 4; ++nr)
                acc[mr][nr] = __builtin_amdgcn_mfma_f32_16x16x32_bf16(a[mr], b[nr], acc[mr][nr], 0, 0, 0);
        __syncthreads();
    }

    // epilogue: C/D layout col = lane&15, row = (lane>>4)*4 + j  [m89/m91]
    #pragma unroll
    for (int nr = 0; nr < 4; ++nr) {
        const int col = n0 + wn * 64 + nr * 16 + fr;
        const float bb = bias[col];
        #pragma unroll
        for (int mr = 0; mr < 4; ++mr) {
            const int rowb = m0 + wm * 64 + mr * 16 + fq * 4;
            #pragma unroll
            for (int j = 0; j < 4; ++j) {
                float v = acc[mr][nr][j] + bb;
                if (RELU) v = fmaxf(v, 0.f);
                if (OUTF) Cf[(size_t)(rowb + j) * N + col] = v;
                if (OUTB) Cb[(size_t)(rowb + j) * N + col] = __float2bfloat16(v);
            }
        }
    }
}

// =====================================================================
// f32 -> bf16 row conversion (optionally fused add), pad rows -> 0
// =====================================================================
template<bool ADD>
__global__ __launch_bounds__(256)
void cvt_bf16_rows(const float* __restrict__ a, const float* __restrict__ a2,
                   __hip_bfloat16* __restrict__ o)
{
    const int i   = blockIdx.x * 256 + threadIdx.x;  // 8-elem chunk id
    const int row = i >> 5;                           // 32 chunks per 256-col row
    union { u4v u; __hip_bfloat16 h[8]; } pk;
    if (row >= NROW) {
        u4v z = {0u, 0u, 0u, 0u};
        pk.u = z;
    } else {
        const size_t e = (size_t)i * 8;
        float4 x0 = *(const float4*)&a[e];
        float4 x1 = *(const float4*)&a[e + 4];
        if (ADD) {
            float4 y0 = *(const float4*)&a2[e];
            float4 y1 = *(const float4*)&a2[e + 4];
            x0.x += y0.x; x0.y += y0.y; x0.z += y0.z; x0.w += y0.w;
            x1.x += y1.x; x1.y += y1.y; x1.z += y1.z; x1.w += y1.w;
        }
        pk.h[0] = __float2bfloat16(x0.x); pk.h[1] = __float2bfloat16(x0.y);
        pk.h[2] = __float2bfloat16(x0.z); pk.h[3] = __float2bfloat16(x0.w);
        pk.h[4] = __float2bfloat16(x1.x); pk.h[5] = __float2bfloat16(x1.y);
        pk.h[6] = __float2bfloat16(x1.z); pk.h[7] = __float2bfloat16(x1.w);
    }
    *(u4v*)&o[(size_t)i * 8] = pk.u;
}

// ---------------- weight transpose + bf16 convert: Wt[n][k] = W[k][n] ----
__global__ __launch_bounds__(256)
void transpose_w(const float* __restrict__ W, __hip_bfloat16* __restrict__ Wt, int K, int N)
{
    const int i = blockIdx.x * 256 + threadIdx.x;
    if (i >= N * K) return;
    const int n = i / K, k = i - n * K;
    Wt[i] = __float2bfloat16(W[(size_t)k * N + n]);
}

// =====================================================================
// MSDA sampling v3: block = 8 rows.
//  phase 1 (256 thr x 4 it): per (r,h,p) softmax weight + 4 corner byte
//           offsets & combined weights -> LDS (p^h XOR-swizzled rows)
//  phase 2: thread = (r, head, channel-oct). 64 x dwordx4 gathers
//           (16B = 8 bf16 channels), 4 lanes/head -> 64B coalesced.
// =====================================================================
__device__ __forceinline__ float blo(unsigned u) { return __builtin_bit_cast(float, u << 16); }
__device__ __forceinline__ float bhi(unsigned u) { return __builtin_bit_cast(float, u & 0xffff0000u); }

__global__ __launch_bounds__(256)
void msda_sample3(const __hip_bfloat16* __restrict__ v, const float* __restrict__ off,
                  const float* __restrict__ awl, const float* __restrict__ refp,
                  __hip_bfloat16* __restrict__ accO)
{
    __shared__ int   sIdx[1024][4];
    __shared__ float sW[1024][4];
    const int row0 = blockIdx.x * 8;
    const int tid  = threadIdx.x;

    #pragma unroll
    for (int it = 0; it < 4; ++it) {
        const int item = it * 256 + tid;          // (r<<7)|(h<<4)|p
        const int p = item & 15, h = (item >> 4) & 7, r = item >> 7;
        const int row = row0 + r;
        const int lvl = p >> 2;
        const float logit = awl[(size_t)row * 128 + h * 16 + p];
        float mx = logit;
        #pragma unroll
        for (int o = 1; o < 16; o <<= 1) mx = fmaxf(mx, __shfl_xor(mx, o, 64));
        const float e = __expf(logit - mx);
        float s = e;
        #pragma unroll
        for (int o = 1; o < 16; o <<= 1) s += __shfl_xor(s, o, 64);
        const float aw = e / s;

        const int Hs[4] = {100, 50, 25, 13};          // square levels
        const int Ss[4] = {0, 10000, 12500, 13125};
        const int   Wl = Hs[lvl];
        const float Wf = (float)Wl;
        const float ox = off[(size_t)row * 256 + h * 32 + p * 2 + 0];
        const float oy = off[(size_t)row * 256 + h * 32 + p * 2 + 1];
        const float rx = refp[(size_t)row * 8 + lvl * 2 + 0];
        const float ry = refp[(size_t)row * 8 + lvl * 2 + 1];
        const float x = (rx + ox / Wf) * Wf - 0.5f;   // keep reference op order
        const float y = (ry + oy / Wf) * Wf - 0.5f;
        const float x0f = floorf(x), y0f = floorf(y);
        const float lx = x - x0f, ly = y - y0f;
        const int x0 = (int)x0f, y0 = (int)y0f;
        const int b = row / Ll;
        const int vbase = b * Ll + Ss[lvl];
        int ixr[4]; float wr[4];
        #pragma unroll
        for (int c = 0; c < 4; ++c) {
            const int cy = c >> 1, cx = c & 1;
            const int yi = y0 + cy, xi = x0 + cx;
            const bool ok = (yi >= 0) & (yi < Wl) & (xi >= 0) & (xi < Wl);
            const int yc = min(max(yi, 0), Wl - 1);
            const int xc = min(max(xi, 0), Wl - 1);
            const float wt = (cy ? ly : 1.f - ly) * (cx ? lx : 1.f - lx);
            ixr[c] = (vbase + yc * Wl + xc) * 512;    // byte offset of v-row
            wr[c]  = ok ? aw * wt : 0.f;
        }
        const int item2 = (item & ~15) | ((item & 15) ^ h);  // bank swizzle
        *(int4*)&sIdx[item2][0] = make_int4(ixr[0], ixr[1], ixr[2], ixr[3]);
        *(float4*)&sW[item2][0] = make_float4(wr[0], wr[1], wr[2], wr[3]);
    }
    __syncthreads();

    const int r   = tid >> 5;
    const int h   = (tid >> 2) & 7;
    const int oct = tid & 3;
    const int row = row0 + r;
    const char* vB = (const char*)v + (h * 32 + oct * 8) * 2;
    const int ibase = r * 128 + h * 16;
    float acc[8] = {};
    #pragma unroll
    for (int i = 0; i < 16; ++i) {
        const int idx = ibase + (i ^ h);
        const int4   ix = *(const int4*)&sIdx[idx][0];
        const float4 wv = *(const float4*)&sW[idx][0];
        u4v u0 = *(const u4v*)(vB + (unsigned)ix.x);
        u4v u1 = *(const u4v*)(vB + (unsigned)ix.y);
        u4v u2 = *(const u4v*)(vB + (unsigned)ix.z);
        u4v u3 = *(const u4v*)(vB + (unsigned)ix.w);
        #pragma unroll
        for (int q = 0; q < 4; ++q) {
            acc[2*q]   = fmaf(wv.x, blo(u0[q]), acc[2*q]);
            acc[2*q+1] = fmaf(wv.x, bhi(u0[q]), acc[2*q+1]);
            acc[2*q]   = fmaf(wv.y, blo(u1[q]), acc[2*q]);
            acc[2*q+1] = fmaf(wv.y, bhi(u1[q]), acc[2*q+1]);
            acc[2*q]   = fmaf(wv.z, blo(u2[q]), acc[2*q]);
            acc[2*q+1] = fmaf(wv.z, bhi(u2[q]), acc[2*q+1]);
            acc[2*q]   = fmaf(wv.w, blo(u3[q]), acc[2*q]);
            acc[2*q+1] = fmaf(wv.w, bhi(u3[q]), acc[2*q+1]);
        }
    }
    union { u4v u; __hip_bfloat16 hh[8]; } pk;
    #pragma unroll
    for (int q = 0; q < 8; ++q) pk.hh[q] = __float2bfloat16(acc[q]);
    *(u4v*)&accO[(size_t)row * 256 + h * 32 + oct * 8] = pk.u;
}

// =====================================================================
// residual + LayerNorm; optional bf16 copy of output; pad rows -> 0
// =====================================================================
template<bool WB>
__global__ __launch_bounds__(256)
void ln_fused2(const float* __restrict__ a, const float* __restrict__ res,
               const float* __restrict__ g, const float* __restrict__ be,
               float* __restrict__ outF, __hip_bfloat16* __restrict__ outB,
               int Mreal, int Mtot)
{
    const int lane = threadIdx.x & 63;
    const int wv   = threadIdx.x >> 6;
    const int row  = blockIdx.x * 4 + wv;
    if (row >= Mtot) return;
    const size_t base = (size_t)row * 256 + lane * 4;
    if (row >= Mreal) {
        float4 z = make_float4(0.f, 0.f, 0.f, 0.f);
        *(float4*)&outF[base] = z;
        if (WB) { union { ushort4 u; __hip_bfloat16 h[4]; } pk;
                  pk.h[0] = pk.h[1] = pk.h[2] = pk.h[3] = __float2bfloat16(0.f);
                  *(ushort4*)&outB[base] = pk.u; }
        return;
    }
    float4 x1 = *(const float4*)&a[base];
    float4 x2 = *(const float4*)&res[base];
    float xs[4] = {x1.x + x2.x, x1.y + x2.y, x1.z + x2.z, x1.w + x2.w};
    float s = xs[0] + xs[1] + xs[2] + xs[3];
    float q = xs[0]*xs[0] + xs[1]*xs[1] + xs[2]*xs[2] + xs[3]*xs[3];
    #pragma unroll
    for (int o = 32; o >= 1; o >>= 1) {
        s += __shfl_xor(s, o, 64);
        q += __shfl_xor(q, o, 64);
    }
    const float mean = s * (1.f / 256.f);
    const float var  = q * (1.f / 256.f) - mean * mean;
    const float r    = rsqrtf(var + 1e-5f);
    float4 gv = *(const float4*)&g[lane * 4];
    float4 bv = *(const float4*)&be[lane * 4];
    float o0 = (xs[0] - mean) * r * gv.x + bv.x;
    float o1 = (xs[1] - mean) * r * gv.y + bv.y;
    float o2 = (xs[2] - mean) * r * gv.z + bv.z;
    float o3 = (xs[3] - mean) * r * gv.w + bv.w;
    float4 o4 = make_float4(o0, o1, o2, o3);
    *(float4*)&outF[base] = o4;
    if (WB) {
        union { ushort4 u; __hip_bfloat16 h[4]; } pk;
        pk.h[0] = __float2bfloat16(o0); pk.h[1] = __float2bfloat16(o1);
        pk.h[2] = __float2bfloat16(o2); pk.h[3] = __float2bfloat16(o3);
        *(ushort4*)&outB[base] = pk.u;
    }
}

// =====================================================================
// launcher
// =====================================================================
extern "C" void kernel_launch(void* const* d_in, const int* in_sizes, int n_in,
                              void* d_out, int out_size, void* d_ws, size_t ws_size,
                              hipStream_t stream)
{
    (void)in_sizes; (void)n_in; (void)out_size; (void)ws_size;
    const float* query = (const float*)d_in[0];
    const float* qpos  = (const float*)d_in[1];
    const float* refp  = (const float*)d_in[2];
    const float* v_W   = (const float*)d_in[5];
    const float* v_b   = (const float*)d_in[6];
    const float* off_W = (const float*)d_in[7];
    const float* off_b = (const float*)d_in[8];
    const float* aw_W  = (const float*)d_in[9];
    const float* aw_b  = (const float*)d_in[10];
    const float* out_W = (const float*)d_in[11];
    const float* out_b = (const float*)d_in[12];
    const float* ln1g  = (const float*)d_in[13];
    const float* ln1b  = (const float*)d_in[14];
    const float* w1    = (const float*)d_in[15];
    const float* b1    = (const float*)d_in[16];
    const float* w2    = (const float*)d_in[17];
    const float* b2    = (const float*)d_in[18];
    const float* ln2g  = (const float*)d_in[19];
    const float* ln2b  = (const float*)d_in[20];
    float* out = (float*)d_out;

    char* ws = (char*)d_ws;
    const size_t SZp = (size_t)MP * 256 * 4;   // 54,525,952 B
    // live-range slot plan (peak 3*SZp + 1.5 MB ~= 165 MB):
    float*          offb = (float*)(ws);                                // [0, 1.0)
    float*          awlb = (float*)(ws + SZp);                          // [1.0, 1.5)
    __hip_bfloat16* qb   = (__hip_bfloat16*)(ws + SZp + SZp / 2);       // [1.5, 2.0)
    __hip_bfloat16* qpb  = (__hip_bfloat16*)(ws + 2 * SZp);             // [2.0, 2.5)
    __hip_bfloat16* vbuf = (__hip_bfloat16*)(ws + 2 * SZp + SZp / 2);   // [2.5, 3.0)
    __hip_bfloat16* accb = qb;                                          // qb dead
    float*          src2 = (float*)(ws);                                // offb dead
    float*          xf   = (float*)(ws + SZp);                          // awlb/accb dead
    __hip_bfloat16* xb   = (__hip_bfloat16*)(ws + 2 * SZp);             // qpb dead
    __hip_bfloat16* hbuf = (__hip_bfloat16*)(ws);                       // src2 dead
    float*          f2f  = (float*)(ws + 2 * SZp + SZp / 2);            // vbuf dead
    char* wsw = ws + 3 * SZp;
    __hip_bfloat16* vWt   = (__hip_bfloat16*)(wsw);
    __hip_bfloat16* offWt = (__hip_bfloat16*)(wsw + 131072);
    __hip_bfloat16* awWt  = (__hip_bfloat16*)(wsw + 262144);
    __hip_bfloat16* outWt = (__hip_bfloat16*)(wsw + 327680);
    __hip_bfloat16* w1t   = (__hip_bfloat16*)(wsw + 458752);
    __hip_bfloat16* w2t   = (__hip_bfloat16*)(wsw + 983040);

    dim3 blk(256);

    // weights -> bf16 transposed
    transpose_w<<<256,  blk, 0, stream>>>(v_W,   vWt,   256, 256);
    transpose_w<<<256,  blk, 0, stream>>>(off_W, offWt, 256, 256);
    transpose_w<<<128,  blk, 0, stream>>>(aw_W,  awWt,  256, 128);
    transpose_w<<<256,  blk, 0, stream>>>(out_W, outWt, 256, 256);
    transpose_w<<<1024, blk, 0, stream>>>(w1,    w1t,   256, 1024);
    transpose_w<<<1024, blk, 0, stream>>>(w2,    w2t,   1024, 256);
    // activations -> bf16 (padded)
    cvt_bf16_rows<false><<<MP / 8, blk, 0, stream>>>(query, nullptr, qb);
    cvt_bf16_rows<true ><<<MP / 8, blk, 0, stream>>>(query, qpos, qpb);

    // projections
    gemm_mfma<false, false, true><<<dim3(2, MP / 128), blk, 0, stream>>>(
        qb, vWt, v_b, nullptr, vbuf, MP, 256, 256);
    gemm_mfma<false, true, false><<<dim3(2, MP / 128), blk, 0, stream>>>(
        qpb, offWt, off_b, offb, nullptr, MP, 256, 256);
    gemm_mfma<false, true, false><<<dim3(1, MP / 128), blk, 0, stream>>>(
        qpb, awWt, aw_b, awlb, nullptr, MP, 128, 256);

    // deformable sampling (8 rows per block; 53176/8 = 6647 exactly)
    msda_sample3<<<NROW / 8, blk, 0, stream>>>(vbuf, offb, awlb, refp, accb);

    // output projection + LN1
    gemm_mfma<false, true, false><<<dim3(2, MP / 128), blk, 0, stream>>>(
        accb, outWt, out_b, src2, nullptr, MP, 256, 256);
    ln_fused2<true><<<MP / 4, blk, 0, stream>>>(query, src2, ln1g, ln1b, xf, xb, NROW, MP);

    // FFN in 2 row-chunks + LN2
    for (int c = 0; c < 2; ++c) {
        gemm_mfma<true, false, true><<<dim3(8, CRp / 128), blk, 0, stream>>>(
            xb + (size_t)c * CRp * 256, w1t, b1, nullptr, hbuf, CRp, 1024, 256);
        gemm_mfma<false, true, false><<<dim3(2, CRp / 128), blk, 0, stream>>>(
            hbuf, w2t, b2, f2f, nullptr, CRp, 256, 1024);
        const int rr = (c == 0) ? CRp : (NROW - CRp);
        ln_fused2<false><<<(rr + 3) / 4, blk, 0, stream>>>(
            xf + (size_t)c * CRp * 256, f2f, ln2g, ln2b,
            out + (size_t)c * CRp * 256, nullptr, rr, rr);
    }
}